// Round 5
// baseline (3746.230 us; speedup 1.0000x reference)
//
#include <hip/hip_runtime.h>

typedef unsigned short ushort_t;
typedef _Float16 half_t;
typedef __attribute__((ext_vector_type(8))) _Float16 half8;
typedef __attribute__((ext_vector_type(4))) float f32x4;

#define B_ 256
#define T_ 200
#define X_ 128
#define H_ 512

// ---- weight store layout: BYTE offsets into d_ws (mixed fp8/f16) ----
// fp8 e4m3 (ODE branch, dt-damped):
#define OFF_WO1 0         //  57344 B  (512x112 fp8, scale 2^13)
#define OFF_WO2 57344     //  65536 B  (128x512 fp8, scale 2^12)
// f16 (everything else):
#define OFF_WU1 122880    // 258048 B
#define OFF_WR1 380928
#define OFF_WN1 638976
#define OFF_WU2 897024
#define OFF_WR2 1028096
#define OFF_WN2 1159168
#define OFF_WT1 1421312
#define OFF_WT2 1650688
#define OFF_WT3 1679360
#define WS_BYTES 1941504
#define DTS_BYTE_OFF WS_BYTES

#define SWZ_ELEMS 1032192
#define INV_WO1 1.220703125e-4f   // 2^-13
#define INV_WO2 2.44140625e-4f    // 2^-12

#define LOG2E 1.4426950408889634f

// ===== r22: fp8 Tier A (ODE branch S1+S2) — port-BW model probe. Ledger: ==
//  Model: per-step per-CU B-stream = 1508KB through ~60B/cy L2 port = 25.5k
//  cy of the 42k-cy step -> port-bound. Only fewer bytes helps (r15/r16
//  showed rebalancing is conserved). fp8 halves bytes; MFMA count unchanged.
//  Tier A = S1/S2 only: output scaled by dt (~0.005) -> quant error ~1e-4,
//  provably safe. Serves as the model probe: -3-5% predicted. If flat ->
//  port model wrong, close fp8 line. If confirmed -> Tier B (Wu1/Wr1/Wn1,
//  -15%) next round. absmax calibrates Tier B risk.
//  r12/r14/r18/r19/r20: VGPR budget immovable at 64; deep unroll CLOSED.
//  r15 split-K CLOSED. r16 x-hoist CLOSED.
//  r21 (kept): S6->S0 barrier merge; x_{t+1} prefetch after S0 barrier
//  (before the barrier its vmcnt(0) drain killed the overlap). 3504us steady.
//  Tripwires: LDS ~61.7KB (layout took), WRITE_SIZE ~3MB (no spill),
//  absmax <= ~3e-3.

struct Args {
  const float *x_data, *x_time;
  const float *Wu1, *bu1, *Wu2, *bu2;
  const float *Wr1, *br1, *Wr2, *br2;
  const float *Wn1, *bn1, *Wn2, *bn2;
  const float *Wo1, *bo1, *Wo2, *bo2;
  const float *Wt1, *bt1, *Wt2, *bt2, *Wt3, *bt3;
  float* out;          // f32 output: mu[256*512] then sigma[256*512]
  unsigned char* wsw;  // swizzled weights (mixed fp8/f16), byte offsets above
  float* dts;          // 200 per-step dt values
};

// hw-instruction activations (validated r12/r13: VALU -70%, absmax unchanged)
__device__ __forceinline__ float fast_sigm(float x) {
  return __builtin_amdgcn_rcpf(1.0f + __builtin_amdgcn_exp2f(-LOG2E * x));
}
__device__ __forceinline__ float fast_tanh(float x) {
  return 1.0f - 2.0f * __builtin_amdgcn_rcpf(1.0f + __builtin_amdgcn_exp2f((2.0f * LOG2E) * x));
}
__device__ __forceinline__ unsigned char f32_to_fp8(float x) {
  return (unsigned char)(__builtin_amdgcn_cvt_pk_fp8_f32(x, x, 0, false) & 0xff);
}

// f16 16x16 tile, K = KB*32. A from LDS, B pre-swizzled global. unroll 4
// (deep unroll closed: r12/r18/r19/r20 all spill at the immovable 64-VGPR cap)
template <int KB>
__device__ __forceinline__ f32x4 gemm_tile(const half_t* __restrict__ wtile,
                                           const half_t* __restrict__ abase,
                                           int astride, int lane, f32x4 acc) {
  const half_t* ap = abase + (lane & 15) * astride + 8 * (lane >> 4);
  const half_t* wp = wtile + lane * 8;
#pragma unroll 4
  for (int kb = 0; kb < KB; ++kb) {
    half8 af = *(const half8*)(ap + kb * 32);
    half8 bf = *(const half8*)(wp + kb * 512);
    acc = __builtin_amdgcn_mfma_f32_16x16x32_f16(af, bf, acc, 0, 0, 0);
  }
  return acc;
}

// fp8 variant: same geometry (K=32/instr, 8 elems/lane), half the bytes.
// astride in BYTES. K-permutation consistency: A and B use the same
// lane->k convention, so any within-group reorder cancels in the product.
template <int KB>
__device__ __forceinline__ f32x4 gemm_tile8(const unsigned char* __restrict__ wtile,
                                            const unsigned char* __restrict__ abase,
                                            int astride, int lane, f32x4 acc) {
  const unsigned char* ap = abase + (lane & 15) * astride + 8 * (lane >> 4);
  const unsigned char* wp = wtile + lane * 8;
#pragma unroll 4
  for (int kb = 0; kb < KB; ++kb) {
    long af = *(const long*)(ap + kb * 32);
    long bf = *(const long*)(wp + kb * 512);
    acc = __builtin_amdgcn_mfma_f32_16x16x32_fp8_fp8(af, bf, acc, 0, 0, 0);
  }
  return acc;
}

// Pre-swizzle f32 weights into MFMA B-fragment layout. Wo1/Wo2 -> fp8 e4m3
// with power-of-2 scale (range maps into normals, max < 448); rest -> f16.
// K padded to mult of 32 (zeros), N padded to mult of 16 (zeros).
__global__ void swz_kernel(Args a) {
  struct WT { const float* src; int eoff; int boff; int KB; int Kr; int Nr;
              int esz; float scale; };
  const WT tbl[11] = {
      {a.Wo1, 0,      OFF_WO1, 16, 512, 100,  1, 8192.0f},
      {a.Wo2, 57344,  OFF_WO2, 4,  100, 512,  1, 4096.0f},
      {a.Wu1, 122880, OFF_WU1, 36, 1152, 100, 2, 1.0f},
      {a.Wr1, 251904, OFF_WR1, 36, 1152, 100, 2, 1.0f},
      {a.Wn1, 380928, OFF_WN1, 36, 1152, 100, 2, 1.0f},
      {a.Wu2, 509952, OFF_WU2, 4,  100, 512,  2, 1.0f},
      {a.Wr2, 575488, OFF_WR2, 4,  100, 512,  2, 1.0f},
      {a.Wn2, 641024, OFF_WN2, 4,  100, 1024, 2, 1.0f},
      {a.Wt1, 772096, OFF_WT1, 32, 1024, 100, 2, 1.0f},
      {a.Wt2, 886784, OFF_WT2, 4,  100, 100,  2, 1.0f},
      {a.Wt3, 901120, OFF_WT3, 4,  100, 1024, 2, 1.0f}};
  const int ends[11] = {57344, 122880, 251904, 380928, 509952, 575488,
                        641024, 772096, 886784, 901120, 1032192};
  int gid = blockIdx.x * blockDim.x + threadIdx.x;
  int e8 = gid * 8;
  if (e8 >= SWZ_ELEMS) return;
  int w = 0;
  while (e8 >= ends[w]) ++w;
  const WT T = tbl[w];
  int local = e8 - T.eoff;
  int lane = (local >> 3) & 63;
  int blk = local >> 9;  // nt*KB + kb
  int kb = blk % T.KB, nt = blk / T.KB;
  int n = nt * 16 + (lane & 15);
  int k0 = kb * 32 + 8 * (lane >> 4);
  float v[8];
#pragma unroll
  for (int j = 0; j < 8; ++j) {
    int k = k0 + j;
    v[j] = (k < T.Kr && n < T.Nr) ? T.src[k * T.Nr + n] * T.scale : 0.0f;
  }
  if (T.esz == 1) {
    int lo = __builtin_amdgcn_cvt_pk_fp8_f32(v[0], v[1], 0, false);
    lo = __builtin_amdgcn_cvt_pk_fp8_f32(v[2], v[3], lo, true);
    int hi = __builtin_amdgcn_cvt_pk_fp8_f32(v[4], v[5], 0, false);
    hi = __builtin_amdgcn_cvt_pk_fp8_f32(v[6], v[7], hi, true);
    int* dst = (int*)(a.wsw + T.boff + local);
    dst[0] = lo;
    dst[1] = hi;
  } else {
    half_t* dst = (half_t*)(a.wsw + T.boff) + local;
#pragma unroll
    for (int j = 0; j < 8; ++j) dst[j] = (half_t)v[j];
  }
}

__global__ void dts_kernel(Args a) {
  int t = threadIdx.x;
  if (t >= T_) return;
  float v;
  if (t == 0)      v = -0.01f;
  else if (t == 1) v = a.x_time[T_ - 1] - a.x_time[0];
  else             v = a.x_time[t - 2] - a.x_time[t - 1];
  a.dts[t] = v;
}

// Persistent ODE-GRU scan: 16 blocks x 1024 threads; block b owns batch rows
// [16b,16b+16). State in registers at C-fragment positions:
//   hreg[s*4+i] = h[m=g*4+i][n=(wave+s*16)*16+lm]  (s=0,1)
__global__ __launch_bounds__(1024) void odegru_kernel(Args a) {
  // yc stride 1160 f16: [h_ode(S2) | hs(S0) | x(S0)]; cols 0-1023 become c
  // after S4. h for S1 lives in yh8 (fp8) instead.
  __shared__ __align__(16) half_t yc[16 * 1160];
  __shared__ __align__(16) unsigned char yh8[16 * 520];  // fp8 h for S1
  __shared__ __align__(16) unsigned char tg8[16 * 136];  // fp8 tg for S2
  __shared__ __align__(16) half_t tu[16 * 136];
  __shared__ __align__(16) half_t tr[16 * 136];
  __shared__ __align__(16) half_t tn[16 * 136];
  __shared__ float dts_s[T_];

  const int tid = threadIdx.x;
  const int wave = tid >> 6;
  const int lane = tid & 63;
  const int lm = lane & 15;
  const int g = lane >> 4;
  const int row0 = blockIdx.x * 16;

  for (int i = tid; i < 16 * 136; i += 1024) {
    tg8[i] = 0; tu[i] = (half_t)0.f; tr[i] = (half_t)0.f; tn[i] = (half_t)0.f;
  }
  if (tid < T_) dts_s[tid] = a.dts[tid];

  // x prefetch: thread covers (xm, xk) and (xm+8, xk); 2048 elems per step.
  const int xm = tid >> 7, xk = tid & 127;
  const float* xb0 = a.x_data + (long)(row0 + xm) * T_ * X_ + xk;
  const float* xb1 = xb0 + (long)8 * T_ * X_;
  float xp0 = xb0[0];  // t = 0 (exposed once, before the loop)
  float xp1 = xb1[0];

  float hreg[8], hsreg[8];
#pragma unroll
  for (int i = 0; i < 8; ++i) { hreg[i] = 0.f; hsreg[i] = 0.f; }
  float ureg[8];  // u gate: producer wave == consumer wave
  __syncthreads();

  for (int t = 0; t < T_; ++t) {
    const float dt = dts_s[t];
    // ---- S0: yh8 = fp8(h); yc.hs = f16(hs); yc.x = f16(x_t)
    //      (merged with S6 tail: S6 reads tn/regs only)
#pragma unroll
    for (int s = 0; s < 2; ++s) {
      int n = (wave + s * 16) * 16 + lm;
#pragma unroll
      for (int i = 0; i < 4; ++i) {
        int m = g * 4 + i;
        yh8[m * 520 + n]       = f32_to_fp8(hreg[s * 4 + i]);
        yc[m * 1160 + 512 + n] = (half_t)hsreg[s * 4 + i];
      }
    }
    yc[xm * 1160 + 1024 + xk]       = (half_t)xp0;
    yc[(xm + 8) * 1160 + 1024 + xk] = (half_t)xp1;
    __syncthreads();
    // x_{t+1} prefetch after the barrier: drains at the end-of-S1 barrier,
    // hiding the HBM miss under S1's MFMA work (r21-validated placement).
    if (t + 1 < T_) {
      xp0 = xb0[(t + 1) * X_];
      xp1 = xb1[(t + 1) * X_];
    }
    // ---- S1 (fp8): tg = tanh(h @ Wo1 + bo1) ----
    for (int nt = wave; nt < 7; nt += 16) {
      f32x4 acc = {0.f, 0.f, 0.f, 0.f};
      acc = gemm_tile8<16>(a.wsw + OFF_WO1 + nt * 16 * 512, yh8, 520, lane, acc);
      int n = nt * 16 + lm;
      if (n < 100) {
        float bias = a.bo1[n];
#pragma unroll
        for (int i = 0; i < 4; ++i)
          tg8[(g * 4 + i) * 136 + n] = f32_to_fp8(fast_tanh(acc[i] * INV_WO1 + bias));
      }
    }
    __syncthreads();
    // ---- S2 (fp8): h_ode = h + dt*(tg @ Wo2 + bo2); yc.h := f16(h_ode) ----
#pragma unroll
    for (int s = 0; s < 2; ++s) {
      int nt = wave + s * 16;
      f32x4 acc = {0.f, 0.f, 0.f, 0.f};
      acc = gemm_tile8<4>(a.wsw + OFF_WO2 + nt * 4 * 512, tg8, 136, lane, acc);
      int n = nt * 16 + lm;
      float bias = a.bo2[n];
#pragma unroll
      for (int i = 0; i < 4; ++i) {
        int m = g * 4 + i;
        float h_ode = hreg[s * 4 + i] + dt * (acc[i] * INV_WO2 + bias);
        hreg[s * 4 + i] = h_ode;
        yc[m * 1160 + n] = (half_t)h_ode;
      }
    }
    __syncthreads();
    // ---- S3: tu = tanh(yc@Wu1+bu1), tr = tanh(yc@Wr1+br1) (14 tiles) ----
    for (int nt = wave; nt < 14; nt += 16) {
      bool isU = nt < 7;
      int nt7 = isU ? nt : nt - 7;
      f32x4 acc = {0.f, 0.f, 0.f, 0.f};
      acc = gemm_tile<36>((const half_t*)(a.wsw + (isU ? OFF_WU1 : OFF_WR1)) + nt7 * 36 * 512,
                          yc, 1160, lane, acc);
      int n = nt7 * 16 + lm;
      if (n < 100) {
        float bias = (isU ? a.bu1 : a.br1)[n];
        half_t* dst = isU ? tu : tr;
#pragma unroll
        for (int i = 0; i < 4; ++i)
          dst[(g * 4 + i) * 136 + n] = (half_t)fast_tanh(acc[i] + bias);
      }
    }
    __syncthreads();
    // ---- S4: u -> ureg ; r -> fused c-build into yc ----
#pragma unroll
    for (int s = 0; s < 2; ++s) {
      int nt = wave + s * 16;
      f32x4 acc = {0.f, 0.f, 0.f, 0.f};
      acc = gemm_tile<4>((const half_t*)(a.wsw + OFF_WU2) + nt * 4 * 512, tu, 136, lane, acc);
      int n = nt * 16 + lm;
      float bias = a.bu2[n];
#pragma unroll
      for (int i = 0; i < 4; ++i) ureg[s * 4 + i] = fast_sigm(acc[i] + bias);
    }
#pragma unroll
    for (int s = 0; s < 2; ++s) {
      int nt = wave + s * 16;
      f32x4 acc = {0.f, 0.f, 0.f, 0.f};
      acc = gemm_tile<4>((const half_t*)(a.wsw + OFF_WR2) + nt * 4 * 512, tr, 136, lane, acc);
      int n = nt * 16 + lm;
      float bias = a.br2[n];
#pragma unroll
      for (int i = 0; i < 4; ++i) {
        int m = g * 4 + i;
        float r = fast_sigm(acc[i] + bias);
        yc[m * 1160 + n]       = (half_t)(hreg[s * 4 + i] * r);
        yc[m * 1160 + 512 + n] = (half_t)(hsreg[s * 4 + i] * r);
      }
    }
    __syncthreads();
    // ---- S5: tn = tanh(c @ Wn1 + bn1) ----
    for (int nt = wave; nt < 7; nt += 16) {
      f32x4 acc = {0.f, 0.f, 0.f, 0.f};
      acc = gemm_tile<36>((const half_t*)(a.wsw + OFF_WN1) + nt * 36 * 512, yc, 1160, lane, acc);
      int n = nt * 16 + lm;
      if (n < 100) {
        float bias = a.bn1[n];
#pragma unroll
        for (int i = 0; i < 4; ++i)
          tn[(g * 4 + i) * 136 + n] = (half_t)fast_tanh(acc[i] + bias);
      }
    }
    __syncthreads();
    // ---- S6: ns = tn @ Wn2 + bn2; gated state update in registers ----
    //      (no trailing barrier: merged with next step's S0)
#pragma unroll
    for (int s = 0; s < 4; ++s) {
      int nt = wave + s * 16;
      f32x4 acc = {0.f, 0.f, 0.f, 0.f};
      acc = gemm_tile<4>((const half_t*)(a.wsw + OFF_WN2) + nt * 4 * 512, tn, 136, lane, acc);
      int n = nt * 16 + lm;
      float bias = a.bn2[n];
      if (s < 2) {  // m-part -> h update
#pragma unroll
        for (int i = 0; i < 4; ++i) {
          float u = ureg[s * 4 + i];
          float mval = acc[i] + bias;
          hreg[s * 4 + i] = (1.0f - u) * mval + u * hreg[s * 4 + i];
        }
      } else {      // s-part -> hs update (same n-tile as ureg[s-2])
#pragma unroll
        for (int i = 0; i < 4; ++i) {
          float u = ureg[(s - 2) * 4 + i];
          float sval = fabsf(acc[i] + bias);
          hsreg[(s - 2) * 4 + i] = (1.0f - u) * sval + u * hsreg[(s - 2) * 4 + i];
        }
      }
    }
  }

  // ---- Final decoder ----
#pragma unroll
  for (int s = 0; s < 2; ++s) {
    int n = (wave + s * 16) * 16 + lm;
#pragma unroll
    for (int i = 0; i < 4; ++i) {
      int m = g * 4 + i;
      yc[m * 1160 + n]       = (half_t)hreg[s * 4 + i];
      yc[m * 1160 + 512 + n] = (half_t)hsreg[s * 4 + i];
    }
  }
  __syncthreads();
  for (int nt = wave; nt < 7; nt += 16) {  // z1 = tanh(hcat@Wt1+bt1)
    f32x4 acc = {0.f, 0.f, 0.f, 0.f};
    acc = gemm_tile<32>((const half_t*)(a.wsw + OFF_WT1) + nt * 32 * 512, yc, 1160, lane, acc);
    int n = nt * 16 + lm;
    if (n < 100) {
      float bias = a.bt1[n];
#pragma unroll
      for (int i = 0; i < 4; ++i)
        tu[(g * 4 + i) * 136 + n] = (half_t)fast_tanh(acc[i] + bias);
    }
  }
  __syncthreads();
  for (int nt = wave; nt < 7; nt += 16) {  // z2 = tanh(z1@Wt2+bt2)
    f32x4 acc = {0.f, 0.f, 0.f, 0.f};
    acc = gemm_tile<4>((const half_t*)(a.wsw + OFF_WT2) + nt * 4 * 512, tu, 136, lane, acc);
    int n = nt * 16 + lm;
    if (n < 100) {
      float bias = a.bt2[n];
#pragma unroll
      for (int i = 0; i < 4; ++i)
        tr[(g * 4 + i) * 136 + n] = (half_t)fast_tanh(acc[i] + bias);
    }
  }
  __syncthreads();
#pragma unroll
  for (int s = 0; s < 4; ++s) {  // z3 = z2@Wt3+bt3 -> mu | sigma (f32 out)
    int nt = wave + s * 16;
    f32x4 acc = {0.f, 0.f, 0.f, 0.f};
    acc = gemm_tile<4>((const half_t*)(a.wsw + OFF_WT3) + nt * 4 * 512, tr, 136, lane, acc);
    int n = nt * 16 + lm;
    float bias = a.bt3[n];
#pragma unroll
    for (int i = 0; i < 4; ++i) {
      int grow = row0 + g * 4 + i;
      float val = acc[i] + bias;
      if (n < 512)
        a.out[(size_t)grow * 512 + n] = val;
      else
        a.out[(size_t)(B_ * 512) + (size_t)grow * 512 + (n - 512)] = fabsf(val);
    }
  }
}

extern "C" void kernel_launch(void* const* d_in, const int* in_sizes, int n_in,
                              void* d_out, int out_size, void* d_ws, size_t ws_size,
                              hipStream_t stream) {
  Args a;
  a.x_data = (const float*)d_in[0];
  a.x_time = (const float*)d_in[1];
  a.Wu1 = (const float*)d_in[2];  a.bu1 = (const float*)d_in[3];
  a.Wu2 = (const float*)d_in[4];  a.bu2 = (const float*)d_in[5];
  a.Wr1 = (const float*)d_in[6];  a.br1 = (const float*)d_in[7];
  a.Wr2 = (const float*)d_in[8];  a.br2 = (const float*)d_in[9];
  a.Wn1 = (const float*)d_in[10]; a.bn1 = (const float*)d_in[11];
  a.Wn2 = (const float*)d_in[12]; a.bn2 = (const float*)d_in[13];
  a.Wo1 = (const float*)d_in[14]; a.bo1 = (const float*)d_in[15];
  a.Wo2 = (const float*)d_in[16]; a.bo2 = (const float*)d_in[17];
  a.Wt1 = (const float*)d_in[18]; a.bt1 = (const float*)d_in[19];
  a.Wt2 = (const float*)d_in[20]; a.bt2 = (const float*)d_in[21];
  a.Wt3 = (const float*)d_in[22]; a.bt3 = (const float*)d_in[23];
  a.out = (float*)d_out;
  a.wsw = (unsigned char*)d_ws;
  a.dts = (float*)((char*)d_ws + DTS_BYTE_OFF);

  swz_kernel<<<dim3(504), dim3(256), 0, stream>>>(a);
  dts_kernel<<<dim3(1), dim3(256), 0, stream>>>(a);
  odegru_kernel<<<dim3(16), dim3(1024), 0, stream>>>(a);
}

// Round 6
// 2874.600 us; speedup vs baseline: 1.3032x; 1.3032x over previous
//
#include <hip/hip_runtime.h>

typedef unsigned short ushort_t;
typedef _Float16 half_t;
typedef __attribute__((ext_vector_type(8))) _Float16 half8;
typedef __attribute__((ext_vector_type(4))) float f32x4;

#define B_ 256
#define T_ 200
#define X_ 128
#define H_ 512

// swizzled weight offsets in d_ws (f16 elements)
#define OFF_WO1 0
#define OFF_WO2 57344
#define OFF_WU1 122880
#define OFF_WR1 251904
#define OFF_WN1 380928
#define OFF_WU2 509952
#define OFF_WR2 575488
#define OFF_WN2 641024
#define OFF_WT1 772096
#define OFF_WT2 886784
#define OFF_WT3 901120
#define SWZ_TOTAL 1032192
#define DTS_BYTE_OFF (SWZ_TOTAL * 2)

#define LOG2E 1.4426950408889634f

// ===== r23 = r21 + A-fragment dedup (gemm_tile2 in S2/S4/S6). Ledger: =====
//  r12/r14/r18/r19/r20: VGPR budget immovable at 64; deep unroll CLOSED.
//  r15 split-K CLOSED. r16 x-hoist CLOSED.
//  r21 (kept, 3504us steady): S6->S0 barrier merge (6 barriers/step);
//       x_{t+1} prefetch AFTER the S0 barrier (before it, __syncthreads'
//       vmcnt(0) drain killed the overlap).
//  r22: fp8 on S1/S2: +150us despite halving those phases' L2 bytes. MFMA
//       cycles identical, VALU +330cy/step landed 1:1 on dur. Byte-BW model
//       REFUTED: phases are latency/issue-bound, not byte-bound. fp8 CLOSED.
//  r23: pipe budget per CU-step: LDS 1508 ds_read_b128 x 8cy = 12k cy
//       (+4.5k conflicts) > VALU 6.7k > MFMA 6k. S2/S4/S6 waves re-read the
//       SAME A-panel per n-tile; share one af across 2 accs (gemm_tile2):
//       -288 reads/block/step (-19% LDS pipe) + matching addr VALU.
//       unroll 2 inside pair (af8+bf16+acc8+addr ~38 regs, safe at 64 cap).
//  Tripwires: WRITE_SIZE ~3MB (no spill), conflicts ~1.15e7, absmax 9.8e-4.

struct Args {
  const float *x_data, *x_time;
  const float *Wu1, *bu1, *Wu2, *bu2;
  const float *Wr1, *br1, *Wr2, *br2;
  const float *Wn1, *bn1, *Wn2, *bn2;
  const float *Wo1, *bo1, *Wo2, *bo2;
  const float *Wt1, *bt1, *Wt2, *bt2, *Wt3, *bt3;
  float* out;      // f32 output: mu[256*512] then sigma[256*512]
  half_t* wsw;     // swizzled weights (f16)
  float* dts;      // 200 per-step dt values
};

// hw-instruction activations (validated r12/r13: VALU -70%, absmax unchanged)
__device__ __forceinline__ float fast_sigm(float x) {
  return __builtin_amdgcn_rcpf(1.0f + __builtin_amdgcn_exp2f(-LOG2E * x));
}
__device__ __forceinline__ float fast_tanh(float x) {
  return 1.0f - 2.0f * __builtin_amdgcn_rcpf(1.0f + __builtin_amdgcn_exp2f((2.0f * LOG2E) * x));
}

// One 16x16 output tile, K = KB*32. A from LDS, B from pre-swizzled global.
// Keep "#pragma unroll 4" (deep unroll closed: r12/r18/r19/r20 all spill).
template <int KB>
__device__ __forceinline__ f32x4 gemm_tile(const half_t* __restrict__ wtile,
                                           const half_t* __restrict__ abase,
                                           int astride, int lane, f32x4 acc) {
  const half_t* ap = abase + (lane & 15) * astride + 8 * (lane >> 4);
  const half_t* wp = wtile + lane * 8;
#pragma unroll 4
  for (int kb = 0; kb < KB; ++kb) {
    half8 af = *(const half8*)(ap + kb * 32);
    half8 bf = *(const half8*)(wp + kb * 512);
    acc = __builtin_amdgcn_mfma_f32_16x16x32_f16(af, bf, acc, 0, 0, 0);
  }
  return acc;
}

// Two tiles sharing one A-fragment load (same A-panel, different B n-tiles).
// Halves the ds_read_b128 count for multi-tile phases (S2/S4/S6). unroll 2:
// af 8 + bf 16 + acc 8 + addr ~= 38 live VGPRs, safe at the 64 cap.
template <int KB>
__device__ __forceinline__ void gemm_tile2(const half_t* __restrict__ w0,
                                           const half_t* __restrict__ w1,
                                           const half_t* __restrict__ abase,
                                           int astride, int lane,
                                           f32x4& acc0, f32x4& acc1) {
  const half_t* ap = abase + (lane & 15) * astride + 8 * (lane >> 4);
  const half_t* wp0 = w0 + lane * 8;
  const half_t* wp1 = w1 + lane * 8;
#pragma unroll 2
  for (int kb = 0; kb < KB; ++kb) {
    half8 af = *(const half8*)(ap + kb * 32);
    half8 b0 = *(const half8*)(wp0 + kb * 512);
    half8 b1 = *(const half8*)(wp1 + kb * 512);
    acc0 = __builtin_amdgcn_mfma_f32_16x16x32_f16(af, b0, acc0, 0, 0, 0);
    acc1 = __builtin_amdgcn_mfma_f32_16x16x32_f16(af, b1, acc1, 0, 0, 0);
  }
}

// Pre-swizzle f32 weights into f16 MFMA B-fragment layout, K padded to mult of
// 32 (zeros), N padded to mult of 16 (zeros).
__global__ void swz_kernel(Args a) {
  struct WT { const float* src; int off; int KB; int Kr; int Nr; };
  const WT tbl[11] = {
      {a.Wo1, OFF_WO1, 16, 512, 100},  {a.Wo2, OFF_WO2, 4, 100, 512},
      {a.Wu1, OFF_WU1, 36, 1152, 100}, {a.Wr1, OFF_WR1, 36, 1152, 100},
      {a.Wn1, OFF_WN1, 36, 1152, 100}, {a.Wu2, OFF_WU2, 4, 100, 512},
      {a.Wr2, OFF_WR2, 4, 100, 512},   {a.Wn2, OFF_WN2, 4, 100, 1024},
      {a.Wt1, OFF_WT1, 32, 1024, 100}, {a.Wt2, OFF_WT2, 4, 100, 100},
      {a.Wt3, OFF_WT3, 4, 100, 1024}};
  const int ends[11] = {OFF_WO2, OFF_WU1, OFF_WR1, OFF_WN1, OFF_WU2, OFF_WR2,
                        OFF_WN2, OFF_WT1, OFF_WT2, OFF_WT3, SWZ_TOTAL};
  int gid = blockIdx.x * blockDim.x + threadIdx.x;
  int e8 = gid * 8;
  if (e8 >= SWZ_TOTAL) return;
  int w = 0;
  while (e8 >= ends[w]) ++w;
  const WT T = tbl[w];
  int local = e8 - T.off;
  int lane = (local >> 3) & 63;
  int blk = local >> 9;  // nt*KB + kb
  int kb = blk % T.KB, nt = blk / T.KB;
  int n = nt * 16 + (lane & 15);
  int k0 = kb * 32 + 8 * (lane >> 4);
#pragma unroll
  for (int j = 0; j < 8; ++j) {
    int k = k0 + j;
    float v = (k < T.Kr && n < T.Nr) ? T.src[k * T.Nr + n] : 0.0f;
    a.wsw[e8 + j] = (half_t)v;
  }
}

__global__ void dts_kernel(Args a) {
  int t = threadIdx.x;
  if (t >= T_) return;
  float v;
  if (t == 0)      v = -0.01f;
  else if (t == 1) v = a.x_time[T_ - 1] - a.x_time[0];
  else             v = a.x_time[t - 2] - a.x_time[t - 1];
  a.dts[t] = v;
}

// Persistent ODE-GRU scan: 16 blocks x 1024 threads; block b owns batch rows
// [16b,16b+16). State in registers at C-fragment positions:
//   hreg[s*4+i] = h[m=g*4+i][n=(wave+s*16)*16+lm]  (s=0,1)
__global__ __launch_bounds__(1024) void odegru_kernel(Args a) {
  // yc stride 1160 f16 (=580 dw == 4 mod 32 -> 2-way-free LDS banks)
  __shared__ __align__(16) half_t yc[16 * 1160];   // [h_ode | hs | x] then c
  __shared__ __align__(16) half_t tg[16 * 136];
  __shared__ __align__(16) half_t tu[16 * 136];
  __shared__ __align__(16) half_t tr[16 * 136];
  __shared__ __align__(16) half_t tn[16 * 136];
  __shared__ float dts_s[T_];

  const int tid = threadIdx.x;
  const int wave = tid >> 6;
  const int lane = tid & 63;
  const int lm = lane & 15;
  const int g = lane >> 4;
  const int row0 = blockIdx.x * 16;

  for (int i = tid; i < 16 * 136; i += 1024) {
    tg[i] = (half_t)0.f; tu[i] = (half_t)0.f; tr[i] = (half_t)0.f; tn[i] = (half_t)0.f;
  }
  if (tid < T_) dts_s[tid] = a.dts[tid];

  // x prefetch: thread covers (xm, xk) and (xm+8, xk); 2048 elems per step.
  const int xm = tid >> 7, xk = tid & 127;
  const float* xb0 = a.x_data + (long)(row0 + xm) * T_ * X_ + xk;
  const float* xb1 = xb0 + (long)8 * T_ * X_;
  float xp0 = xb0[0];  // t = 0 (exposed once, before the loop)
  float xp1 = xb1[0];

  float hreg[8], hsreg[8];
#pragma unroll
  for (int i = 0; i < 8; ++i) { hreg[i] = 0.f; hsreg[i] = 0.f; }
  float ureg[8];  // u gate: producer wave == consumer wave
  __syncthreads();

  for (int t = 0; t < T_; ++t) {
    const float dt = dts_s[t];
    // ---- S0: yc = [f16(h) | f16(hs) | f16(x_t)] (merged with S6 tail:
    //          no barrier between S6 and S0 — S6 reads tn/regs, S0 writes yc;
    //          S5's yc reads are fenced by the S5->S6 barrier)
#pragma unroll
    for (int s = 0; s < 2; ++s) {
      int n = (wave + s * 16) * 16 + lm;
#pragma unroll
      for (int i = 0; i < 4; ++i) {
        int m = g * 4 + i;
        yc[m * 1160 + n]       = (half_t)hreg[s * 4 + i];
        yc[m * 1160 + 512 + n] = (half_t)hsreg[s * 4 + i];
      }
    }
    yc[xm * 1160 + 1024 + xk]       = (half_t)xp0;
    yc[(xm + 8) * 1160 + 1024 + xk] = (half_t)xp1;
    __syncthreads();
    // x_{t+1} prefetch issued AFTER the barrier: drains at the end-of-S1
    // barrier, i.e. the HBM miss hides under S1's MFMA work.
    if (t + 1 < T_) {
      xp0 = xb0[(t + 1) * X_];
      xp1 = xb1[(t + 1) * X_];
    }
    // ---- S1: tg = tanh(h @ Wo1 + bo1) ----
    for (int nt = wave; nt < 7; nt += 16) {
      f32x4 acc = {0.f, 0.f, 0.f, 0.f};
      acc = gemm_tile<16>(a.wsw + OFF_WO1 + nt * 16 * 512, yc, 1160, lane, acc);
      int n = nt * 16 + lm;
      if (n < 100) {
        float bias = a.bo1[n];
#pragma unroll
        for (int i = 0; i < 4; ++i)
          tg[(g * 4 + i) * 136 + n] = (half_t)fast_tanh(acc[i] + bias);
      }
    }
    __syncthreads();
    // ---- S2: h_ode = h + dt*(tg @ Wo2 + bo2); hreg := h_ode; yc := f16(h_ode)
    //      (pair-tile: one af read feeds both s=0/s=1 accumulators) ----
    {
      f32x4 acc0 = {0.f, 0.f, 0.f, 0.f}, acc1 = {0.f, 0.f, 0.f, 0.f};
      gemm_tile2<4>(a.wsw + OFF_WO2 + wave * 4 * 512,
                    a.wsw + OFF_WO2 + (wave + 16) * 4 * 512,
                    tg, 136, lane, acc0, acc1);
#pragma unroll
      for (int s = 0; s < 2; ++s) {
        const f32x4& acc = s ? acc1 : acc0;
        int n = (wave + s * 16) * 16 + lm;
        float bias = a.bo2[n];
#pragma unroll
        for (int i = 0; i < 4; ++i) {
          int m = g * 4 + i;
          float h_ode = hreg[s * 4 + i] + dt * (acc[i] + bias);
          hreg[s * 4 + i] = h_ode;
          yc[m * 1160 + n] = (half_t)h_ode;
        }
      }
    }
    __syncthreads();
    // ---- S3: tu = tanh(yc@Wu1+bu1), tr = tanh(yc@Wr1+br1) (14 tiles) ----
    for (int nt = wave; nt < 14; nt += 16) {
      bool isU = nt < 7;
      int nt7 = isU ? nt : nt - 7;
      f32x4 acc = {0.f, 0.f, 0.f, 0.f};
      acc = gemm_tile<36>(a.wsw + (isU ? OFF_WU1 : OFF_WR1) + nt7 * 36 * 512, yc, 1160, lane, acc);
      int n = nt7 * 16 + lm;
      if (n < 100) {
        float bias = (isU ? a.bu1 : a.br1)[n];
        half_t* dst = isU ? tu : tr;
#pragma unroll
        for (int i = 0; i < 4; ++i)
          dst[(g * 4 + i) * 136 + n] = (half_t)fast_tanh(acc[i] + bias);
      }
    }
    __syncthreads();
    // ---- S4: u -> ureg ; r -> fused c-build into yc (pair-tile af sharing) --
    {
      f32x4 acc0 = {0.f, 0.f, 0.f, 0.f}, acc1 = {0.f, 0.f, 0.f, 0.f};
      gemm_tile2<4>(a.wsw + OFF_WU2 + wave * 4 * 512,
                    a.wsw + OFF_WU2 + (wave + 16) * 4 * 512,
                    tu, 136, lane, acc0, acc1);
#pragma unroll
      for (int s = 0; s < 2; ++s) {
        const f32x4& acc = s ? acc1 : acc0;
        int n = (wave + s * 16) * 16 + lm;
        float bias = a.bu2[n];
#pragma unroll
        for (int i = 0; i < 4; ++i) ureg[s * 4 + i] = fast_sigm(acc[i] + bias);
      }
    }
    {
      f32x4 acc0 = {0.f, 0.f, 0.f, 0.f}, acc1 = {0.f, 0.f, 0.f, 0.f};
      gemm_tile2<4>(a.wsw + OFF_WR2 + wave * 4 * 512,
                    a.wsw + OFF_WR2 + (wave + 16) * 4 * 512,
                    tr, 136, lane, acc0, acc1);
#pragma unroll
      for (int s = 0; s < 2; ++s) {
        const f32x4& acc = s ? acc1 : acc0;
        int n = (wave + s * 16) * 16 + lm;
        float bias = a.br2[n];
#pragma unroll
        for (int i = 0; i < 4; ++i) {
          int m = g * 4 + i;
          float r = fast_sigm(acc[i] + bias);
          yc[m * 1160 + n]       = (half_t)(hreg[s * 4 + i] * r);
          yc[m * 1160 + 512 + n] = (half_t)(hsreg[s * 4 + i] * r);
        }
      }
    }
    __syncthreads();
    // ---- S5: tn = tanh(c @ Wn1 + bn1) ----
    for (int nt = wave; nt < 7; nt += 16) {
      f32x4 acc = {0.f, 0.f, 0.f, 0.f};
      acc = gemm_tile<36>(a.wsw + OFF_WN1 + nt * 36 * 512, yc, 1160, lane, acc);
      int n = nt * 16 + lm;
      if (n < 100) {
        float bias = a.bn1[n];
#pragma unroll
        for (int i = 0; i < 4; ++i)
          tn[(g * 4 + i) * 136 + n] = (half_t)fast_tanh(acc[i] + bias);
      }
    }
    __syncthreads();
    // ---- S6: ns = tn @ Wn2 + bn2; gated state update (2x pair-tile) ----
    //      (no trailing barrier: merged with next step's S0)
    {
      f32x4 acc0 = {0.f, 0.f, 0.f, 0.f}, acc1 = {0.f, 0.f, 0.f, 0.f};
      gemm_tile2<4>(a.wsw + OFF_WN2 + wave * 4 * 512,
                    a.wsw + OFF_WN2 + (wave + 16) * 4 * 512,
                    tn, 136, lane, acc0, acc1);
#pragma unroll
      for (int s = 0; s < 2; ++s) {  // m-part -> h update
        const f32x4& acc = s ? acc1 : acc0;
        int n = (wave + s * 16) * 16 + lm;
        float bias = a.bn2[n];
#pragma unroll
        for (int i = 0; i < 4; ++i) {
          float u = ureg[s * 4 + i];
          float mval = acc[i] + bias;
          hreg[s * 4 + i] = (1.0f - u) * mval + u * hreg[s * 4 + i];
        }
      }
    }
    {
      f32x4 acc0 = {0.f, 0.f, 0.f, 0.f}, acc1 = {0.f, 0.f, 0.f, 0.f};
      gemm_tile2<4>(a.wsw + OFF_WN2 + (wave + 32) * 4 * 512,
                    a.wsw + OFF_WN2 + (wave + 48) * 4 * 512,
                    tn, 136, lane, acc0, acc1);
#pragma unroll
      for (int s = 0; s < 2; ++s) {  // s-part -> hs update
        const f32x4& acc = s ? acc1 : acc0;
        int n = (wave + 32 + s * 16) * 16 + lm;
        float bias = a.bn2[n];
#pragma unroll
        for (int i = 0; i < 4; ++i) {
          float u = ureg[s * 4 + i];
          float sval = fabsf(acc[i] + bias);
          hsreg[s * 4 + i] = (1.0f - u) * sval + u * hsreg[s * 4 + i];
        }
      }
    }
  }

  // ---- Final decoder ----
#pragma unroll
  for (int s = 0; s < 2; ++s) {
    int n = (wave + s * 16) * 16 + lm;
#pragma unroll
    for (int i = 0; i < 4; ++i) {
      int m = g * 4 + i;
      yc[m * 1160 + n]       = (half_t)hreg[s * 4 + i];
      yc[m * 1160 + 512 + n] = (half_t)hsreg[s * 4 + i];
    }
  }
  __syncthreads();
  for (int nt = wave; nt < 7; nt += 16) {  // z1 = tanh(hcat@Wt1+bt1)
    f32x4 acc = {0.f, 0.f, 0.f, 0.f};
    acc = gemm_tile<32>(a.wsw + OFF_WT1 + nt * 32 * 512, yc, 1160, lane, acc);
    int n = nt * 16 + lm;
    if (n < 100) {
      float bias = a.bt1[n];
#pragma unroll
      for (int i = 0; i < 4; ++i)
        tu[(g * 4 + i) * 136 + n] = (half_t)fast_tanh(acc[i] + bias);
    }
  }
  __syncthreads();
  for (int nt = wave; nt < 7; nt += 16) {  // z2 = tanh(z1@Wt2+bt2)
    f32x4 acc = {0.f, 0.f, 0.f, 0.f};
    acc = gemm_tile<4>(a.wsw + OFF_WT2 + nt * 4 * 512, tu, 136, lane, acc);
    int n = nt * 16 + lm;
    if (n < 100) {
      float bias = a.bt2[n];
#pragma unroll
      for (int i = 0; i < 4; ++i)
        tr[(g * 4 + i) * 136 + n] = (half_t)fast_tanh(acc[i] + bias);
    }
  }
  __syncthreads();
#pragma unroll
  for (int s = 0; s < 4; ++s) {  // z3 = z2@Wt3+bt3 -> mu | sigma (f32 out)
    int nt = wave + s * 16;
    f32x4 acc = {0.f, 0.f, 0.f, 0.f};
    acc = gemm_tile<4>(a.wsw + OFF_WT3 + nt * 4 * 512, tr, 136, lane, acc);
    int n = nt * 16 + lm;
    float bias = a.bt3[n];
#pragma unroll
    for (int i = 0; i < 4; ++i) {
      int grow = row0 + g * 4 + i;
      float val = acc[i] + bias;
      if (n < 512)
        a.out[(size_t)grow * 512 + n] = val;
      else
        a.out[(size_t)(B_ * 512) + (size_t)grow * 512 + (n - 512)] = fabsf(val);
    }
  }
}

extern "C" void kernel_launch(void* const* d_in, const int* in_sizes, int n_in,
                              void* d_out, int out_size, void* d_ws, size_t ws_size,
                              hipStream_t stream) {
  Args a;
  a.x_data = (const float*)d_in[0];
  a.x_time = (const float*)d_in[1];
  a.Wu1 = (const float*)d_in[2];  a.bu1 = (const float*)d_in[3];
  a.Wu2 = (const float*)d_in[4];  a.bu2 = (const float*)d_in[5];
  a.Wr1 = (const float*)d_in[6];  a.br1 = (const float*)d_in[7];
  a.Wr2 = (const float*)d_in[8];  a.br2 = (const float*)d_in[9];
  a.Wn1 = (const float*)d_in[10]; a.bn1 = (const float*)d_in[11];
  a.Wn2 = (const float*)d_in[12]; a.bn2 = (const float*)d_in[13];
  a.Wo1 = (const float*)d_in[14]; a.bo1 = (const float*)d_in[15];
  a.Wo2 = (const float*)d_in[16]; a.bo2 = (const float*)d_in[17];
  a.Wt1 = (const float*)d_in[18]; a.bt1 = (const float*)d_in[19];
  a.Wt2 = (const float*)d_in[20]; a.bt2 = (const float*)d_in[21];
  a.Wt3 = (const float*)d_in[22]; a.bt3 = (const float*)d_in[23];
  a.out = (float*)d_out;
  a.wsw = (half_t*)d_ws;
  a.dts = (float*)((char*)d_ws + DTS_BYTE_OFF);

  swz_kernel<<<dim3(504), dim3(256), 0, stream>>>(a);
  dts_kernel<<<dim3(1), dim3(256), 0, stream>>>(a);
  odegru_kernel<<<dim3(16), dim3(1024), 0, stream>>>(a);
}